// Round 5
// baseline (507.917 us; speedup 1.0000x reference)
//
#include <hip/hip_runtime.h>

// NeuralFieldCosmo — R5: fragment-resident MFMA + LDS-staged W3 frags +
// software-pipelined loads.
// Wave = 16 edges (edge = lane&15 = MFMA tile column). Channels in lane-quads
// (MFMA 16x16x16 bf16: C row = 4q+reg, A/B k = 4q+j), so LN output feeds the
// next GEMM's B-fragment in-register.
// R4 failure: ~176 VGPR of "resident" constants vs 128-VGPR file -> compiler
// re-gathered W3 from global every tile; unprefetched dependent loads ->
// latency-bound (all pipes <25%). R5: W3/b3 frags in LDS (16.5 KB, ds_read
// per tile), other consts packed bf16 (<=128 VGPR honest), next-tile loads
// issued one iteration early.

typedef __attribute__((ext_vector_type(4))) short short4v;   // 4 bf16
typedef __attribute__((ext_vector_type(4))) float float4v;
typedef __attribute__((ext_vector_type(4))) unsigned uint4v;
typedef __attribute__((ext_vector_type(2))) unsigned uint2v;

constexpr float LN_EPS   = 1e-5f;
constexpr float LOG2E_X2 = 2.8853900817779268f;  // 2*log2(e)

__device__ __forceinline__ float fast_tanh(float x) {
  float e = __builtin_amdgcn_exp2f(x * LOG2E_X2);
  return 1.0f - 2.0f * __builtin_amdgcn_rcpf(e + 1.0f);
}

// RNE float -> bf16 bits
__device__ __forceinline__ unsigned f2bf(float x) {
  unsigned u = __builtin_bit_cast(unsigned, x);
  u += 0x7FFFu + ((u >> 16) & 1u);
  return u >> 16;
}
__device__ __forceinline__ unsigned pack2(float lo, float hi) {
  return f2bf(lo) | (f2bf(hi) << 16);
}
__device__ __forceinline__ float bflo2f(unsigned u) {
  return __builtin_bit_cast(float, u << 16);
}
__device__ __forceinline__ float bfhi2f(unsigned u) {
  return __builtin_bit_cast(float, u & 0xFFFF0000u);
}

__device__ __forceinline__ float4v mfma16(short4v a, short4v b, float4v c) {
#if __has_builtin(__builtin_amdgcn_mfma_f32_16x16x16bf16_1k)
  return __builtin_amdgcn_mfma_f32_16x16x16bf16_1k(a, b, c, 0, 0, 0);
#else
  float4v d;
  asm volatile("v_mfma_f32_16x16x16_bf16 %0, %1, %2, %3\n\ts_nop 7\n\ts_nop 7"
               : "=&v"(d) : "v"(a), "v"(b), "v"(c));
  return d;
#endif
}

// LN over 32 ch (8/lane across quads), affine(packed bf16 g,be), relu,
// pack to two K-half B-frags. Single reduction phase: sum & sumsq interleaved.
__device__ __forceinline__ void ln_relu_pack(const float* hv, const unsigned* gp,
                                             const unsigned* bp, short4v* bh) {
  float sum = 0.f, ss = 0.f;
#pragma unroll
  for (int s = 0; s < 8; ++s) { sum += hv[s]; ss += hv[s] * hv[s]; }
  sum += __shfl_xor(sum, 16);  ss += __shfl_xor(ss, 16);
  sum += __shfl_xor(sum, 32);  ss += __shfl_xor(ss, 32);
  const float m   = sum * (1.0f / 32.0f);
  const float var = fmaxf(ss * (1.0f / 32.0f) - m * m, 0.f);
  const float rs  = rsqrtf(var + LN_EPS);
#pragma unroll
  for (int h = 0; h < 2; ++h) {
    short4v v;
#pragma unroll
    for (int j = 0; j < 4; ++j) {
      const int s = h * 4 + j;
      const float g  = (s & 1) ? bfhi2f(gp[s >> 1]) : bflo2f(gp[s >> 1]);
      const float be = (s & 1) ? bfhi2f(bp[s >> 1]) : bflo2f(bp[s >> 1]);
      float y = (hv[s] - m) * rs * g + be;
      v[j] = (short)f2bf(fmaxf(y, 0.f));
    }
    bh[h] = v;
  }
}

// ---------------- CSR build ----------------

__global__ void nf_hist(const int* __restrict__ out_edges, int* __restrict__ counts, int E) {
  int stride = gridDim.x * blockDim.x;
  for (int e = blockIdx.x * blockDim.x + threadIdx.x; e < E; e += stride)
    atomicAdd(&counts[out_edges[e]], 1);
}

// disjoint-range allocation (order-free): wave scan + one atomic per wave
__global__ void nf_alloc(const int* __restrict__ counts, int* __restrict__ offsets,
                         int* __restrict__ cursor, int* __restrict__ total, int N) {
  const int i = blockIdx.x * blockDim.x + threadIdx.x;
  const int lane = threadIdx.x & 63;
  int c = (i < N) ? counts[i] : 0;
  int sc = c;
#pragma unroll
  for (int d = 1; d < 64; d <<= 1) {
    int v = __shfl_up(sc, d);
    if (lane >= d) sc += v;
  }
  const int excl = sc - c;
  const int wtot = __shfl(sc, 63);
  int base = 0;
  if (lane == 0) base = atomicAdd(total, wtot);
  base = __shfl(base, 0);
  if (i < N) {
    offsets[i] = base + excl;
    cursor[i]  = base + excl;
  }
}

// ---------------- main compute ----------------
// SCATTER_MODE: 0 = CSR (stream out_ch + bucket), 1 = direct atomics fallback

template <int SCATTER_MODE>
__global__ __launch_bounds__(256, 4)   // pin 4 waves/SIMD; VGPR cap 128
void nf_main(const int* __restrict__ in_edges,
             const int* __restrict__ out_edges,
             const float* __restrict__ ef,
             const float* __restrict__ coords,
             const float* __restrict__ W1, const float* __restrict__ b1,
             const float* __restrict__ g1, const float* __restrict__ be1,
             const float* __restrict__ W2, const float* __restrict__ b2,
             const float* __restrict__ g2, const float* __restrict__ be2,
             const float* __restrict__ W3, const float* __restrict__ b3,
             float* __restrict__ out_ch,  // mode0: [E][16] ; mode1: sums (d_out)
             int* __restrict__ bucket,    // mode0: [E]     ; mode1: counts
             int* __restrict__ cursor,    // mode0: [N]
             int E, int ntiles)
{
  // W3 A-fragments, per (o, lane): 16B = 8 bf16 {k = 4q+j+16h}
  __shared__ __align__(16) unsigned sA3[16 * 64 * 4];   // [o][lane][4] = 16 KB
  __shared__ __align__(8)  unsigned sB3[16 * 4 * 2];    // [o][quad][2] = 512 B

  const int t    = threadIdx.x;
  const int l    = t & 63;
  const int q    = l >> 4;     // lane quad (channel/row group)
  const int ecol = l & 15;     // edge column within tile

  // ---- one-time LDS staging of W3/b3 fragments ----
#pragma unroll
  for (int rep = 0; rep < 4; ++rep) {
    const int idx = rep * 256 + t;          // (o, lane)
    const int o = idx >> 6, ll = idx & 63;
    const int qq = ll >> 4, ec = ll & 15;
    uint4v w;
#pragma unroll
    for (int h = 0; h < 2; ++h)
#pragma unroll
      for (int jp = 0; jp < 2; ++jp) {
        const float lo = W3[(4 * qq + 2 * jp     + 16 * h) * 256 + o * 16 + ec];
        const float hi = W3[(4 * qq + 2 * jp + 1 + 16 * h) * 256 + o * 16 + ec];
        w[h * 2 + jp] = pack2(lo, hi);
      }
    *(uint4v*)&sA3[idx * 4] = w;
  }
  if (t < 64) {
    const int o = t >> 2, qq = t & 3;
    sB3[t * 2]     = pack2(b3[o * 16 + 4 * qq + 0], b3[o * 16 + 4 * qq + 1]);
    sB3[t * 2 + 1] = pack2(b3[o * 16 + 4 * qq + 2], b3[o * 16 + 4 * qq + 3]);
  }

  // ---- per-lane packed constants (bf16 pairs; ~44 VGPR) ----
  // lane's 8 channels: ch(s) = 4q + (s&3) + 16*(s>>2); pairs (2i, 2i+1)
  unsigned w1p[3][4], b1p[4], g1p[4], be1p[4], b2p[4], g2p[4], be2p[4];
#pragma unroll
  for (int i = 0; i < 4; ++i) {
    const int s0 = 2 * i, s1 = 2 * i + 1;
    const int c0 = 4 * q + (s0 & 3) + 16 * (s0 >> 2);
    const int c1 = 4 * q + (s1 & 3) + 16 * (s1 >> 2);
    w1p[0][i] = pack2(W1[c0],      W1[c1]);
    w1p[1][i] = pack2(W1[32 + c0], W1[32 + c1]);
    w1p[2][i] = pack2(W1[64 + c0], W1[64 + c1]);
    b1p[i]  = pack2(b1[c0],  b1[c1]);
    g1p[i]  = pack2(g1[c0],  g1[c1]);
    be1p[i] = pack2(be1[c0], be1[c1]);
    b2p[i]  = pack2(b2[c0],  b2[c1]);
    g2p[i]  = pack2(g2[c0],  g2[c1]);
    be2p[i] = pack2(be2[c0], be2[c1]);
  }
  // L2 A-frags: A'[m=ch_out][k=ch_in] = W2[k][m]; m = ecol+16*t2, k = 4q+j+16h
  short4v a2[2][2];
#pragma unroll
  for (int t2 = 0; t2 < 2; ++t2)
#pragma unroll
    for (int h = 0; h < 2; ++h) {
      short4v v;
#pragma unroll
      for (int j = 0; j < 4; ++j)
        v[j] = (short)f2bf(W2[(4 * q + j + 16 * h) * 32 + ecol + 16 * t2]);
      a2[t2][h] = v;
    }

  __syncthreads();

  const int gwave  = (blockIdx.x * blockDim.x + t) >> 6;
  const int nwaves = (gridDim.x * blockDim.x) >> 6;

  // ---- prologue: load tile-0 state ----
  int tile = gwave;
  bool valid = false; int eIdx = 0, ie = 0, oe = 0;
  float x0 = 0.f, x1 = 0.f, x2 = 0.f;
  float4v f4 = {};
  if (tile < ntiles) {
    eIdx  = tile * 16 + ecol;
    valid = eIdx < E;
    const int eS = valid ? eIdx : 0;
    ie = in_edges[eS]; oe = out_edges[eS];
    x0 = coords[3 * eS]; x1 = coords[3 * eS + 1]; x2 = coords[3 * eS + 2];
    f4 = *(const float4v*)(ef + (size_t)ie * 16 + 4 * q);
  }

  for (; tile < ntiles; tile += nwaves) {
    // ---- prefetch next tile's indices + coords (consumed next iter) ----
    const int tn = tile + nwaves;
    int eIdxN = 0, ieN = 0, oeN = 0; bool validN = false;
    float x0N = 0.f, x1N = 0.f, x2N = 0.f;
    if (tn < ntiles) {
      eIdxN  = tn * 16 + ecol;
      validN = eIdxN < E;
      const int eSN = validN ? eIdxN : 0;
      ieN = in_edges[eSN]; oeN = out_edges[eSN];
      x0N = coords[3 * eSN]; x1N = coords[3 * eSN + 1]; x2N = coords[3 * eSN + 2];
    }

    // bucket slot for CURRENT tile — atomic latency hides under the MLP
    int pos = 0;
    if (SCATTER_MODE == 0 && q == 0 && valid)
      pos = atomicAdd(&cursor[oe], 1);

    // ---- L1: 3 -> 32 (f32, packed weights) ----
    float hv[8];
#pragma unroll
    for (int i = 0; i < 4; ++i) {
      hv[2 * i]     = bflo2f(b1p[i]) + x0 * bflo2f(w1p[0][i])
                    + x1 * bflo2f(w1p[1][i]) + x2 * bflo2f(w1p[2][i]);
      hv[2 * i + 1] = bfhi2f(b1p[i]) + x0 * bfhi2f(w1p[0][i])
                    + x1 * bfhi2f(w1p[1][i]) + x2 * bfhi2f(w1p[2][i]);
    }
    short4v bh[2];
    ln_relu_pack(hv, g1p, be1p, bh);

    // ---- L2 GEMM: 32->32 ----
#pragma unroll
    for (int t2 = 0; t2 < 2; ++t2) {
      float4v c;
      c[0] = bflo2f(b2p[t2 * 2]);     c[1] = bfhi2f(b2p[t2 * 2]);
      c[2] = bflo2f(b2p[t2 * 2 + 1]); c[3] = bfhi2f(b2p[t2 * 2 + 1]);
      c = mfma16(a2[t2][0], bh[0], c);
      c = mfma16(a2[t2][1], bh[1], c);
      hv[t2 * 4 + 0] = c[0]; hv[t2 * 4 + 1] = c[1];
      hv[t2 * 4 + 2] = c[2]; hv[t2 * 4 + 3] = c[3];
    }
    ln_relu_pack(hv, g2p, be2p, bh);

    // ---- prefetch next tile's feature gather (ieN has landed by now) ----
    float4v f4N = {};
    if (tn < ntiles)
      f4N = *(const float4v*)(ef + (size_t)ieN * 16 + 4 * q);

    // ---- L3 GEMM + tanh + f-contraction, grouped 4 o's at a time ----
#pragma unroll
    for (int og = 0; og < 4; ++og) {
      float pr[4];
#pragma unroll
      for (int r = 0; r < 4; ++r) {
        const int o = og * 4 + r;
        const uint4v av = *(const uint4v*)&sA3[(o * 64 + l) * 4];
        const uint2v bv = *(const uint2v*)&sB3[o * 8 + q * 2];
        uint2v t0; t0[0] = av[0]; t0[1] = av[1];
        uint2v t1; t1[0] = av[2]; t1[1] = av[3];
        const short4v a30 = __builtin_bit_cast(short4v, t0);
        const short4v a31 = __builtin_bit_cast(short4v, t1);
        float4v c;
        c[0] = bflo2f(bv[0]); c[1] = bfhi2f(bv[0]);
        c[2] = bflo2f(bv[1]); c[3] = bfhi2f(bv[1]);
        c = mfma16(a30, bh[0], c);
        c = mfma16(a31, bh[1], c);
        pr[r] = f4[0] * fast_tanh(c[0]) + f4[1] * fast_tanh(c[1])
              + f4[2] * fast_tanh(c[2]) + f4[3] * fast_tanh(c[3]);
      }
#pragma unroll
      for (int r = 0; r < 4; ++r) {
        pr[r] += __shfl_xor(pr[r], 16);
        pr[r] += __shfl_xor(pr[r], 32);
      }
      if (SCATTER_MODE == 0) {
        if (q == 0 && valid) {
          float4v s = {pr[0], pr[1], pr[2], pr[3]};
          *(float4v*)(out_ch + (size_t)eIdx * 16 + og * 4) = s;
        }
      } else {
        if (q == 0 && valid) {
#pragma unroll
          for (int r = 0; r < 4; ++r)
            atomicAdd(&out_ch[(size_t)oe * 16 + og * 4 + r], pr[r]);
        }
      }
    }

    if (SCATTER_MODE == 0) {
      if (q == 0 && valid) bucket[pos] = eIdx;
    } else {
      if (q == 0 && valid) atomicAdd(&bucket[oe], 1);
    }

    // rotate pipeline state
    eIdx = eIdxN; valid = validN; ie = ieN; oe = oeN;
    x0 = x0N; x1 = x1N; x2 = x2N; f4 = f4N;
  }
}

// ---------------- per-node reduce (CSR path) ----------------

__global__ __launch_bounds__(256)
void nf_reduce(const float* __restrict__ out_ch, const int* __restrict__ bucket,
               const int* __restrict__ counts, const int* __restrict__ offsets,
               float* __restrict__ out, int N) {
  const int gid = blockIdx.x * 16 + (threadIdx.x >> 4);
  const int o   = threadIdx.x & 15;
  if (gid >= N) return;
  const int deg = counts[gid];
  const int off = offsets[gid];
  float acc = 0.f;
  for (int d = 0; d < deg; ++d) {
    int eid = bucket[off + d];
    acc += out_ch[(size_t)eid * 16 + o];
  }
  out[(size_t)gid * 16 + o] = acc / fmaxf((float)deg, 1.0f);
}

// fallback divide
__global__ void nf_final(float* __restrict__ out, const int* __restrict__ counts, int n) {
  int i = blockIdx.x * blockDim.x + threadIdx.x;
  if (i < n) {
    float c = (float)counts[i >> 4];
    out[i] = out[i] / fmaxf(c, 1.0f);
  }
}

extern "C" void kernel_launch(void* const* d_in, const int* in_sizes, int n_in,
                              void* d_out, int out_size, void* d_ws, size_t ws_size,
                              hipStream_t stream) {
  const int*   in_edges  = (const int*)d_in[0];
  const int*   out_edges = (const int*)d_in[1];
  const float* ef        = (const float*)d_in[2];
  const float* coords    = (const float*)d_in[3];
  const float* W1  = (const float*)d_in[4];
  const float* b1  = (const float*)d_in[5];
  const float* g1  = (const float*)d_in[6];
  const float* be1 = (const float*)d_in[7];
  const float* W2  = (const float*)d_in[8];
  const float* b2  = (const float*)d_in[9];
  const float* g2  = (const float*)d_in[10];
  const float* be2 = (const float*)d_in[11];
  const float* W3  = (const float*)d_in[12];
  const float* b3  = (const float*)d_in[13];

  const int E = in_sizes[0];
  const int N = in_sizes[2] / 16;
  const int ntiles = (E + 15) / 16;
  float* out = (float*)d_out;

  // ws: out_ch [16E f32] | bucket [E] | counts [N] | offsets [N] | cursor [N] | total [1]
  const size_t need = ((size_t)E * 16 + (size_t)E + 3 * (size_t)N + 1) * 4;

  if (ws_size >= need) {
    float* out_chv = (float*)d_ws;
    int*   bucket  = (int*)(out_chv + (size_t)E * 16);
    int*   counts  = bucket + E;
    int*   offsets = counts + N;
    int*   cursor  = offsets + N;
    int*   total   = cursor + N;

    hipMemsetAsync(counts, 0, ((size_t)3 * N + 1) * sizeof(int), stream);
    nf_hist<<<1024, 256, 0, stream>>>(out_edges, counts, E);
    nf_alloc<<<(N + 255) / 256, 256, 0, stream>>>(counts, offsets, cursor, total, N);
    nf_main<0><<<1024, 256, 0, stream>>>(in_edges, out_edges, ef, coords,
                                         W1, b1, g1, be1, W2, b2, g2, be2, W3, b3,
                                         out_chv, bucket, cursor, E, ntiles);
    nf_reduce<<<(N + 15) / 16, 256, 0, stream>>>(out_chv, bucket, counts, offsets, out, N);
  } else {
    // fallback: direct atomics
    int* counts = (int*)d_ws;
    hipMemsetAsync(out, 0, (size_t)out_size * sizeof(float), stream);
    hipMemsetAsync(counts, 0, (size_t)N * sizeof(int), stream);
    nf_main<1><<<1024, 256, 0, stream>>>(in_edges, out_edges, ef, coords,
                                         W1, b1, g1, be1, W2, b2, g2, be2, W3, b3,
                                         out, counts, nullptr, E, ntiles);
    nf_final<<<(out_size + 255) / 256, 256, 0, stream>>>(out, counts, out_size);
  }
}

// Round 6
// 248.806 us; speedup vs baseline: 2.0414x; 2.0414x over previous
//
#include <hip/hip_runtime.h>

// NeuralFieldCosmo — R6: fragment-resident MFMA, LDS-staged W3 frags AND
// LDS-staged small constants, software-pipelined loads, honest VGPR budget.
//
// History: R4 = consts "in regs" exceeded cap -> per-tile W3 re-gather,
// latency-bound 310us. R5 = W3 to LDS but launch_bounds(256,4) capped VGPR
// at 128 < ~150 live -> spill (VGPR=64, 1.15GB scratch traffic, 420us).
// R6 = cap 256 (launch_bounds(256,2), proven spill-free in R3/R4) + move
// packed LN/L1 constants to LDS (quad-uniform broadcast reads, ~9 ds_read
// per tile) so actual allocation lands ~100-128 VGPR -> 4+ waves/SIMD.

typedef __attribute__((ext_vector_type(4))) short short4v;   // 4 bf16
typedef __attribute__((ext_vector_type(4))) float float4v;
typedef __attribute__((ext_vector_type(4))) unsigned uint4v;
typedef __attribute__((ext_vector_type(2))) unsigned uint2v;

constexpr float LN_EPS   = 1e-5f;
constexpr float LOG2E_X2 = 2.8853900817779268f;  // 2*log2(e)

__device__ __forceinline__ float fast_tanh(float x) {
  float e = __builtin_amdgcn_exp2f(x * LOG2E_X2);
  return 1.0f - 2.0f * __builtin_amdgcn_rcpf(e + 1.0f);
}

// RNE float -> bf16 bits
__device__ __forceinline__ unsigned f2bf(float x) {
  unsigned u = __builtin_bit_cast(unsigned, x);
  u += 0x7FFFu + ((u >> 16) & 1u);
  return u >> 16;
}
__device__ __forceinline__ unsigned pack2(float lo, float hi) {
  return f2bf(lo) | (f2bf(hi) << 16);
}
__device__ __forceinline__ float bflo2f(unsigned u) {
  return __builtin_bit_cast(float, u << 16);
}
__device__ __forceinline__ float bfhi2f(unsigned u) {
  return __builtin_bit_cast(float, u & 0xFFFF0000u);
}

__device__ __forceinline__ float4v mfma16(short4v a, short4v b, float4v c) {
#if __has_builtin(__builtin_amdgcn_mfma_f32_16x16x16bf16_1k)
  return __builtin_amdgcn_mfma_f32_16x16x16bf16_1k(a, b, c, 0, 0, 0);
#else
  float4v d;
  asm volatile("v_mfma_f32_16x16x16_bf16 %0, %1, %2, %3\n\ts_nop 7\n\ts_nop 7"
               : "=&v"(d) : "v"(a), "v"(b), "v"(c));
  return d;
#endif
}

// LN over 32 ch (8/lane across quads), affine (packed bf16 g,be), relu,
// pack to two K-half B-frags. Single reduction phase (sum & sumsq together).
__device__ __forceinline__ void ln_relu_pack(const float* hv, uint4v gp,
                                             uint4v bp, short4v* bh) {
  float sum = 0.f, ss = 0.f;
#pragma unroll
  for (int s = 0; s < 8; ++s) { sum += hv[s]; ss += hv[s] * hv[s]; }
  sum += __shfl_xor(sum, 16);  ss += __shfl_xor(ss, 16);
  sum += __shfl_xor(sum, 32);  ss += __shfl_xor(ss, 32);
  const float m   = sum * (1.0f / 32.0f);
  const float var = fmaxf(ss * (1.0f / 32.0f) - m * m, 0.f);
  const float rs  = rsqrtf(var + LN_EPS);
#pragma unroll
  for (int h = 0; h < 2; ++h) {
    short4v v;
#pragma unroll
    for (int j = 0; j < 4; ++j) {
      const int s = h * 4 + j;
      const float g  = (s & 1) ? bfhi2f(gp[s >> 1]) : bflo2f(gp[s >> 1]);
      const float be = (s & 1) ? bfhi2f(bp[s >> 1]) : bflo2f(bp[s >> 1]);
      float y = (hv[s] - m) * rs * g + be;
      v[j] = (short)f2bf(fmaxf(y, 0.f));
    }
    bh[h] = v;
  }
}

// ---------------- CSR build ----------------

__global__ void nf_hist(const int* __restrict__ out_edges, int* __restrict__ counts, int E) {
  int stride = gridDim.x * blockDim.x;
  for (int e = blockIdx.x * blockDim.x + threadIdx.x; e < E; e += stride)
    atomicAdd(&counts[out_edges[e]], 1);
}

// disjoint-range allocation (order-free): wave scan + one atomic per wave
__global__ void nf_alloc(const int* __restrict__ counts, int* __restrict__ offsets,
                         int* __restrict__ cursor, int* __restrict__ total, int N) {
  const int i = blockIdx.x * blockDim.x + threadIdx.x;
  const int lane = threadIdx.x & 63;
  int c = (i < N) ? counts[i] : 0;
  int sc = c;
#pragma unroll
  for (int d = 1; d < 64; d <<= 1) {
    int v = __shfl_up(sc, d);
    if (lane >= d) sc += v;
  }
  const int excl = sc - c;
  const int wtot = __shfl(sc, 63);
  int base = 0;
  if (lane == 0) base = atomicAdd(total, wtot);
  base = __shfl(base, 0);
  if (i < N) {
    offsets[i] = base + excl;
    cursor[i]  = base + excl;
  }
}

// ---------------- main compute ----------------
// SCATTER_MODE: 0 = CSR (stream out_ch + bucket), 1 = direct atomics fallback

template <int SCATTER_MODE>
__global__ __launch_bounds__(256, 2)   // cap 256 VGPR: NEVER spill (R3/R4 proven)
void nf_main(const int* __restrict__ in_edges,
             const int* __restrict__ out_edges,
             const float* __restrict__ ef,
             const float* __restrict__ coords,
             const float* __restrict__ W1, const float* __restrict__ b1,
             const float* __restrict__ g1, const float* __restrict__ be1,
             const float* __restrict__ W2, const float* __restrict__ b2,
             const float* __restrict__ g2, const float* __restrict__ be2,
             const float* __restrict__ W3, const float* __restrict__ b3,
             float* __restrict__ out_ch,  // mode0: [E][16] ; mode1: sums (d_out)
             int* __restrict__ bucket,    // mode0: [E]     ; mode1: counts
             int* __restrict__ cursor,    // mode0: [N]
             int E, int ntiles)
{
  // W3 A-fragments, per (o, lane): 16B = 8 bf16 {k = 4q+j+16h}
  __shared__ __align__(16) unsigned sA3[16 * 64 * 4];   // 16 KB
  __shared__ __align__(8)  unsigned sB3[16 * 4 * 2];    // 512 B
  // quad-uniform packed constants (bf16 pairs), broadcast ds_reads per tile
  __shared__ __align__(16) unsigned sC1[4][16];  // w1p[3][4], b1p[4]
  __shared__ __align__(16) unsigned sC2[4][16];  // g1p, be1p, g2p, be2p
  __shared__ __align__(16) unsigned sC3[4][4];   // b2p

  const int t    = threadIdx.x;
  const int l    = t & 63;
  const int q    = l >> 4;     // lane quad (channel/row group)
  const int ecol = l & 15;     // edge column within tile

  // ---- one-time LDS staging ----
#pragma unroll
  for (int rep = 0; rep < 4; ++rep) {
    const int idx = rep * 256 + t;          // (o, lane)
    const int o = idx >> 6, ll = idx & 63;
    const int qq = ll >> 4, ec = ll & 15;
    uint4v w;
#pragma unroll
    for (int h = 0; h < 2; ++h)
#pragma unroll
      for (int jp = 0; jp < 2; ++jp) {
        const float lo = W3[(4 * qq + 2 * jp     + 16 * h) * 256 + o * 16 + ec];
        const float hi = W3[(4 * qq + 2 * jp + 1 + 16 * h) * 256 + o * 16 + ec];
        w[h * 2 + jp] = pack2(lo, hi);
      }
    *(uint4v*)&sA3[idx * 4] = w;
  }
  if (t < 64) {
    const int o = t >> 2, qq = t & 3;
    sB3[t * 2]     = pack2(b3[o * 16 + 4 * qq + 0], b3[o * 16 + 4 * qq + 1]);
    sB3[t * 2 + 1] = pack2(b3[o * 16 + 4 * qq + 2], b3[o * 16 + 4 * qq + 3]);
  }
  if (t < 4) {
    const int qq = t;
#pragma unroll
    for (int i = 0; i < 4; ++i) {
      // lane channel pairs: i<2 -> 4q+2i, 4q+2i+1 ; i>=2 -> 4q+16+2(i-2), +1
      const int base = (i < 2) ? (4 * qq + 2 * i) : (4 * qq + 16 + 2 * (i - 2));
      sC1[qq][i]      = pack2(W1[base],      W1[base + 1]);
      sC1[qq][4 + i]  = pack2(W1[32 + base], W1[33 + base]);
      sC1[qq][8 + i]  = pack2(W1[64 + base], W1[65 + base]);
      sC1[qq][12 + i] = pack2(b1[base],      b1[base + 1]);
      sC2[qq][i]      = pack2(g1[base],      g1[base + 1]);
      sC2[qq][4 + i]  = pack2(be1[base],     be1[base + 1]);
      sC2[qq][8 + i]  = pack2(g2[base],      g2[base + 1]);
      sC2[qq][12 + i] = pack2(be2[base],     be2[base + 1]);
      sC3[qq][i]      = pack2(b2[base],      b2[base + 1]);
    }
  }

  // L2 A-frags stay in registers (8 VGPR, used 4x/tile):
  // A'[m=ch_out][k=ch_in] = W2[k][m]; m = ecol+16*t2, k = 4q+j+16h
  short4v a2[2][2];
#pragma unroll
  for (int t2 = 0; t2 < 2; ++t2)
#pragma unroll
    for (int h = 0; h < 2; ++h) {
      short4v v;
#pragma unroll
      for (int j = 0; j < 4; ++j)
        v[j] = (short)f2bf(W2[(4 * q + j + 16 * h) * 32 + ecol + 16 * t2]);
      a2[t2][h] = v;
    }

  __syncthreads();

  const int gwave  = (blockIdx.x * blockDim.x + t) >> 6;
  const int nwaves = (gridDim.x * blockDim.x) >> 6;

  // ---- prologue: load tile-0 state ----
  int tile = gwave;
  bool valid = false; int eIdx = 0, ie = 0, oe = 0;
  float x0 = 0.f, x1 = 0.f, x2 = 0.f;
  float4v f4 = {};
  if (tile < ntiles) {
    eIdx  = tile * 16 + ecol;
    valid = eIdx < E;
    const int eS = valid ? eIdx : 0;
    ie = in_edges[eS]; oe = out_edges[eS];
    x0 = coords[3 * eS]; x1 = coords[3 * eS + 1]; x2 = coords[3 * eS + 2];
    f4 = *(const float4v*)(ef + (size_t)ie * 16 + 4 * q);
  }

  for (; tile < ntiles; tile += nwaves) {
    // ---- prefetch next tile's indices + coords (consumed next iter) ----
    const int tn = tile + nwaves;
    int eIdxN = 0, ieN = 0, oeN = 0; bool validN = false;
    float x0N = 0.f, x1N = 0.f, x2N = 0.f;
    if (tn < ntiles) {
      eIdxN  = tn * 16 + ecol;
      validN = eIdxN < E;
      const int eSN = validN ? eIdxN : 0;
      ieN = in_edges[eSN]; oeN = out_edges[eSN];
      x0N = coords[3 * eSN]; x1N = coords[3 * eSN + 1]; x2N = coords[3 * eSN + 2];
    }

    // bucket slot for CURRENT tile — atomic latency hides under the MLP
    int pos = 0;
    if (SCATTER_MODE == 0 && q == 0 && valid)
      pos = atomicAdd(&cursor[oe], 1);

    // ---- L1: 3 -> 32 (consts via quad-broadcast LDS reads) ----
    const uint4v w1r0 = *(const uint4v*)&sC1[q][0];
    const uint4v w1r1 = *(const uint4v*)&sC1[q][4];
    const uint4v w1r2 = *(const uint4v*)&sC1[q][8];
    const uint4v b1v  = *(const uint4v*)&sC1[q][12];
    float hv[8];
#pragma unroll
    for (int i = 0; i < 4; ++i) {
      hv[2 * i]     = bflo2f(b1v[i]) + x0 * bflo2f(w1r0[i])
                    + x1 * bflo2f(w1r1[i]) + x2 * bflo2f(w1r2[i]);
      hv[2 * i + 1] = bfhi2f(b1v[i]) + x0 * bfhi2f(w1r0[i])
                    + x1 * bfhi2f(w1r1[i]) + x2 * bfhi2f(w1r2[i]);
    }
    short4v bh[2];
    {
      const uint4v g1v  = *(const uint4v*)&sC2[q][0];
      const uint4v be1v = *(const uint4v*)&sC2[q][4];
      ln_relu_pack(hv, g1v, be1v, bh);
    }

    // ---- L2 GEMM: 32->32 ----
    {
      const uint4v b2v = *(const uint4v*)&sC3[q][0];
#pragma unroll
      for (int t2 = 0; t2 < 2; ++t2) {
        float4v c;
        c[0] = bflo2f(b2v[t2 * 2]);     c[1] = bfhi2f(b2v[t2 * 2]);
        c[2] = bflo2f(b2v[t2 * 2 + 1]); c[3] = bfhi2f(b2v[t2 * 2 + 1]);
        c = mfma16(a2[t2][0], bh[0], c);
        c = mfma16(a2[t2][1], bh[1], c);
        hv[t2 * 4 + 0] = c[0]; hv[t2 * 4 + 1] = c[1];
        hv[t2 * 4 + 2] = c[2]; hv[t2 * 4 + 3] = c[3];
      }
    }
    {
      const uint4v g2v  = *(const uint4v*)&sC2[q][8];
      const uint4v be2v = *(const uint4v*)&sC2[q][12];
      ln_relu_pack(hv, g2v, be2v, bh);
    }

    // ---- prefetch next tile's feature gather (ieN has landed by now) ----
    float4v f4N = {};
    if (tn < ntiles)
      f4N = *(const float4v*)(ef + (size_t)ieN * 16 + 4 * q);

    // ---- L3 GEMM + tanh + f-contraction, grouped 4 o's at a time ----
#pragma unroll
    for (int og = 0; og < 4; ++og) {
      float pr[4];
#pragma unroll
      for (int r = 0; r < 4; ++r) {
        const int o = og * 4 + r;
        const uint4v av = *(const uint4v*)&sA3[(o * 64 + l) * 4];
        const uint2v bv = *(const uint2v*)&sB3[o * 8 + q * 2];
        uint2v t0; t0[0] = av[0]; t0[1] = av[1];
        uint2v t1; t1[0] = av[2]; t1[1] = av[3];
        const short4v a30 = __builtin_bit_cast(short4v, t0);
        const short4v a31 = __builtin_bit_cast(short4v, t1);
        float4v c;
        c[0] = bflo2f(bv[0]); c[1] = bfhi2f(bv[0]);
        c[2] = bflo2f(bv[1]); c[3] = bfhi2f(bv[1]);
        c = mfma16(a30, bh[0], c);
        c = mfma16(a31, bh[1], c);
        pr[r] = f4[0] * fast_tanh(c[0]) + f4[1] * fast_tanh(c[1])
              + f4[2] * fast_tanh(c[2]) + f4[3] * fast_tanh(c[3]);
      }
#pragma unroll
      for (int r = 0; r < 4; ++r) {
        pr[r] += __shfl_xor(pr[r], 16);
        pr[r] += __shfl_xor(pr[r], 32);
      }
      if (SCATTER_MODE == 0) {
        if (q == 0 && valid) {
          float4v s = {pr[0], pr[1], pr[2], pr[3]};
          *(float4v*)(out_ch + (size_t)eIdx * 16 + og * 4) = s;
        }
      } else {
        if (q == 0 && valid) {
#pragma unroll
          for (int r = 0; r < 4; ++r)
            atomicAdd(&out_ch[(size_t)oe * 16 + og * 4 + r], pr[r]);
        }
      }
    }

    if (SCATTER_MODE == 0) {
      if (q == 0 && valid) bucket[pos] = eIdx;
    } else {
      if (q == 0 && valid) atomicAdd(&bucket[oe], 1);
    }

    // rotate pipeline state
    eIdx = eIdxN; valid = validN; ie = ieN; oe = oeN;
    x0 = x0N; x1 = x1N; x2 = x2N; f4 = f4N;
  }
}

// ---------------- per-node reduce (CSR path) ----------------

__global__ __launch_bounds__(256)
void nf_reduce(const float* __restrict__ out_ch, const int* __restrict__ bucket,
               const int* __restrict__ counts, const int* __restrict__ offsets,
               float* __restrict__ out, int N) {
  const int gid = blockIdx.x * 16 + (threadIdx.x >> 4);
  const int o   = threadIdx.x & 15;
  if (gid >= N) return;
  const int deg = counts[gid];
  const int off = offsets[gid];
  float acc = 0.f;
  for (int d = 0; d < deg; ++d) {
    int eid = bucket[off + d];
    acc += out_ch[(size_t)eid * 16 + o];
  }
  out[(size_t)gid * 16 + o] = acc / fmaxf((float)deg, 1.0f);
}

// fallback divide
__global__ void nf_final(float* __restrict__ out, const int* __restrict__ counts, int n) {
  int i = blockIdx.x * blockDim.x + threadIdx.x;
  if (i < n) {
    float c = (float)counts[i >> 4];
    out[i] = out[i] / fmaxf(c, 1.0f);
  }
}

extern "C" void kernel_launch(void* const* d_in, const int* in_sizes, int n_in,
                              void* d_out, int out_size, void* d_ws, size_t ws_size,
                              hipStream_t stream) {
  const int*   in_edges  = (const int*)d_in[0];
  const int*   out_edges = (const int*)d_in[1];
  const float* ef        = (const float*)d_in[2];
  const float* coords    = (const float*)d_in[3];
  const float* W1  = (const float*)d_in[4];
  const float* b1  = (const float*)d_in[5];
  const float* g1  = (const float*)d_in[6];
  const float* be1 = (const float*)d_in[7];
  const float* W2  = (const float*)d_in[8];
  const float* b2  = (const float*)d_in[9];
  const float* g2  = (const float*)d_in[10];
  const float* be2 = (const float*)d_in[11];
  const float* W3  = (const float*)d_in[12];
  const float* b3  = (const float*)d_in[13];

  const int E = in_sizes[0];
  const int N = in_sizes[2] / 16;
  const int ntiles = (E + 15) / 16;
  float* out = (float*)d_out;

  // ws: out_ch [16E f32] | bucket [E] | counts [N] | offsets [N] | cursor [N] | total [1]
  const size_t need = ((size_t)E * 16 + (size_t)E + 3 * (size_t)N + 1) * 4;

  if (ws_size >= need) {
    float* out_chv = (float*)d_ws;
    int*   bucket  = (int*)(out_chv + (size_t)E * 16);
    int*   counts  = bucket + E;
    int*   offsets = counts + N;
    int*   cursor  = offsets + N;
    int*   total   = cursor + N;

    hipMemsetAsync(counts, 0, ((size_t)3 * N + 1) * sizeof(int), stream);
    nf_hist<<<1024, 256, 0, stream>>>(out_edges, counts, E);
    nf_alloc<<<(N + 255) / 256, 256, 0, stream>>>(counts, offsets, cursor, total, N);
    nf_main<0><<<2048, 256, 0, stream>>>(in_edges, out_edges, ef, coords,
                                         W1, b1, g1, be1, W2, b2, g2, be2, W3, b3,
                                         out_chv, bucket, cursor, E, ntiles);
    nf_reduce<<<(N + 15) / 16, 256, 0, stream>>>(out_chv, bucket, counts, offsets, out, N);
  } else {
    // fallback: direct atomics
    int* counts = (int*)d_ws;
    hipMemsetAsync(out, 0, (size_t)out_size * sizeof(float), stream);
    hipMemsetAsync(counts, 0, (size_t)N * sizeof(int), stream);
    nf_main<1><<<2048, 256, 0, stream>>>(in_edges, out_edges, ef, coords,
                                         W1, b1, g1, be1, W2, b2, g2, be2, W3, b3,
                                         out, counts, nullptr, E, ntiles);
    nf_final<<<(out_size + 255) / 256, 256, 0, stream>>>(out, counts, out_size);
  }
}

// Round 7
// 234.412 us; speedup vs baseline: 2.1668x; 1.0614x over previous
//
#include <hip/hip_runtime.h>

// NeuralFieldCosmo — R7: fragment-resident MFMA + LDS consts (R6, proven) +
// (a) W3/b3 prescaled by 2*log2e at staging; epilogue algebra
//     sum_i f_i*tanh_i = sumf - 2*sum_i f_i*rcp(exp2(y_i)+1)  (saves mul+unpacks)
// (b) b3 stored f32 in LDS -> MFMA C-init is one ds_read_b128
// (c) CSR-ordered out_ch write (edge row stored at its cursor slot) -> bucket
//     array eliminated; nf_reduce reads each node's rows contiguously.
//
// Residency ledger (hard-won): launch_bounds(256,2) + consts in LDS ->
// VGPR=128, zero spill (R6 counters). Do not tighten the cap (R5 regression),
// do not grow per-lane constant arrays (R4 regression).

typedef __attribute__((ext_vector_type(4))) short short4v;   // 4 bf16
typedef __attribute__((ext_vector_type(4))) float float4v;
typedef __attribute__((ext_vector_type(4))) unsigned uint4v;
typedef __attribute__((ext_vector_type(2))) unsigned uint2v;

constexpr float LN_EPS   = 1e-5f;
constexpr float LOG2E_X2 = 2.8853900817779268f;  // 2*log2(e)

// RNE float -> bf16 bits
__device__ __forceinline__ unsigned f2bf(float x) {
  unsigned u = __builtin_bit_cast(unsigned, x);
  u += 0x7FFFu + ((u >> 16) & 1u);
  return u >> 16;
}
__device__ __forceinline__ unsigned pack2(float lo, float hi) {
  return f2bf(lo) | (f2bf(hi) << 16);
}
__device__ __forceinline__ float bflo2f(unsigned u) {
  return __builtin_bit_cast(float, u << 16);
}
__device__ __forceinline__ float bfhi2f(unsigned u) {
  return __builtin_bit_cast(float, u & 0xFFFF0000u);
}

__device__ __forceinline__ float4v mfma16(short4v a, short4v b, float4v c) {
#if __has_builtin(__builtin_amdgcn_mfma_f32_16x16x16bf16_1k)
  return __builtin_amdgcn_mfma_f32_16x16x16bf16_1k(a, b, c, 0, 0, 0);
#else
  float4v d;
  asm volatile("v_mfma_f32_16x16x16_bf16 %0, %1, %2, %3\n\ts_nop 7\n\ts_nop 7"
               : "=&v"(d) : "v"(a), "v"(b), "v"(c));
  return d;
#endif
}

// LN over 32 ch (8/lane across quads), affine (packed bf16 g,be), relu,
// pack to two K-half B-frags. Single reduction phase (sum & sumsq together).
__device__ __forceinline__ void ln_relu_pack(const float* hv, uint4v gp,
                                             uint4v bp, short4v* bh) {
  float sum = 0.f, ss = 0.f;
#pragma unroll
  for (int s = 0; s < 8; ++s) { sum += hv[s]; ss += hv[s] * hv[s]; }
  sum += __shfl_xor(sum, 16);  ss += __shfl_xor(ss, 16);
  sum += __shfl_xor(sum, 32);  ss += __shfl_xor(ss, 32);
  const float m   = sum * (1.0f / 32.0f);
  const float var = fmaxf(ss * (1.0f / 32.0f) - m * m, 0.f);
  const float rs  = rsqrtf(var + LN_EPS);
#pragma unroll
  for (int h = 0; h < 2; ++h) {
    short4v v;
#pragma unroll
    for (int j = 0; j < 4; ++j) {
      const int s = h * 4 + j;
      const float g  = (s & 1) ? bfhi2f(gp[s >> 1]) : bflo2f(gp[s >> 1]);
      const float be = (s & 1) ? bfhi2f(bp[s >> 1]) : bflo2f(bp[s >> 1]);
      float y = (hv[s] - m) * rs * g + be;
      v[j] = (short)f2bf(fmaxf(y, 0.f));
    }
    bh[h] = v;
  }
}

// ---------------- CSR build ----------------

__global__ void nf_hist(const int* __restrict__ out_edges, int* __restrict__ counts, int E) {
  int stride = gridDim.x * blockDim.x;
  for (int e = blockIdx.x * blockDim.x + threadIdx.x; e < E; e += stride)
    atomicAdd(&counts[out_edges[e]], 1);
}

// disjoint-range allocation (order-free): wave scan + one atomic per wave
__global__ void nf_alloc(const int* __restrict__ counts, int* __restrict__ offsets,
                         int* __restrict__ cursor, int* __restrict__ total, int N) {
  const int i = blockIdx.x * blockDim.x + threadIdx.x;
  const int lane = threadIdx.x & 63;
  int c = (i < N) ? counts[i] : 0;
  int sc = c;
#pragma unroll
  for (int d = 1; d < 64; d <<= 1) {
    int v = __shfl_up(sc, d);
    if (lane >= d) sc += v;
  }
  const int excl = sc - c;
  const int wtot = __shfl(sc, 63);
  int base = 0;
  if (lane == 0) base = atomicAdd(total, wtot);
  base = __shfl(base, 0);
  if (i < N) {
    offsets[i] = base + excl;
    cursor[i]  = base + excl;
  }
}

// ---------------- main compute ----------------
// SCATTER_MODE: 0 = CSR-ordered stream, 1 = direct atomics fallback

template <int SCATTER_MODE>
__global__ __launch_bounds__(256, 2)   // cap 256 VGPR: NEVER spill (R3/R4/R6 proven)
void nf_main(const int* __restrict__ in_edges,
             const int* __restrict__ out_edges,
             const float* __restrict__ ef,
             const float* __restrict__ coords,
             const float* __restrict__ W1, const float* __restrict__ b1,
             const float* __restrict__ g1, const float* __restrict__ be1,
             const float* __restrict__ W2, const float* __restrict__ b2,
             const float* __restrict__ g2, const float* __restrict__ be2,
             const float* __restrict__ W3, const float* __restrict__ b3,
             float* __restrict__ out_ch,  // mode0: [E][16] CSR-ordered ; mode1: sums (d_out)
             int* __restrict__ aux,       // mode0: unused ; mode1: counts
             int* __restrict__ cursor,    // mode0: [N]
             int E, int ntiles)
{
  // W3 A-fragments (prescaled by 2log2e), per (o, lane): 16B = 8 bf16 {k=4q+j+16h}
  __shared__ __align__(16) unsigned sA3[16 * 64 * 4];   // 16 KB
  __shared__ __align__(16) float    sB3f[16 * 4 * 4];   // b3 * 2log2e, f32: 1 KB
  // quad-uniform packed constants (bf16 pairs), broadcast ds_reads per tile
  __shared__ __align__(16) unsigned sC1[4][16];  // w1p[3][4], b1p[4]
  __shared__ __align__(16) unsigned sC2[4][16];  // g1p, be1p, g2p, be2p
  __shared__ __align__(16) unsigned sC3[4][4];   // b2p

  const int t    = threadIdx.x;
  const int l    = t & 63;
  const int q    = l >> 4;     // lane quad (channel/row group)
  const int ecol = l & 15;     // edge column within tile

  // ---- one-time LDS staging ----
#pragma unroll
  for (int rep = 0; rep < 4; ++rep) {
    const int idx = rep * 256 + t;          // (o, lane)
    const int o = idx >> 6, ll = idx & 63;
    const int qq = ll >> 4, ec = ll & 15;
    uint4v w;
#pragma unroll
    for (int h = 0; h < 2; ++h)
#pragma unroll
      for (int jp = 0; jp < 2; ++jp) {
        const float lo = LOG2E_X2 * W3[(4 * qq + 2 * jp     + 16 * h) * 256 + o * 16 + ec];
        const float hi = LOG2E_X2 * W3[(4 * qq + 2 * jp + 1 + 16 * h) * 256 + o * 16 + ec];
        w[h * 2 + jp] = pack2(lo, hi);
      }
    *(uint4v*)&sA3[idx * 4] = w;
  }
  if (t < 64) {
    const int o = t >> 2, qq = t & 3;
    float4v bb;
#pragma unroll
    for (int r = 0; r < 4; ++r) bb[r] = LOG2E_X2 * b3[o * 16 + 4 * qq + r];
    *(float4v*)&sB3f[t * 4] = bb;
  }
  if (t < 4) {
    const int qq = t;
#pragma unroll
    for (int i = 0; i < 4; ++i) {
      const int base = (i < 2) ? (4 * qq + 2 * i) : (4 * qq + 16 + 2 * (i - 2));
      sC1[qq][i]      = pack2(W1[base],      W1[base + 1]);
      sC1[qq][4 + i]  = pack2(W1[32 + base], W1[33 + base]);
      sC1[qq][8 + i]  = pack2(W1[64 + base], W1[65 + base]);
      sC1[qq][12 + i] = pack2(b1[base],      b1[base + 1]);
      sC2[qq][i]      = pack2(g1[base],      g1[base + 1]);
      sC2[qq][4 + i]  = pack2(be1[base],     be1[base + 1]);
      sC2[qq][8 + i]  = pack2(g2[base],      g2[base + 1]);
      sC2[qq][12 + i] = pack2(be2[base],     be2[base + 1]);
      sC3[qq][i]      = pack2(b2[base],      b2[base + 1]);
    }
  }

  // L2 A-frags in registers (8 VGPR): A'[m=ch_out][k=ch_in] = W2[k][m]
  short4v a2[2][2];
#pragma unroll
  for (int t2 = 0; t2 < 2; ++t2)
#pragma unroll
    for (int h = 0; h < 2; ++h) {
      short4v v;
#pragma unroll
      for (int j = 0; j < 4; ++j)
        v[j] = (short)f2bf(W2[(4 * q + j + 16 * h) * 32 + ecol + 16 * t2]);
      a2[t2][h] = v;
    }

  __syncthreads();

  const int gwave  = (blockIdx.x * blockDim.x + t) >> 6;
  const int nwaves = (gridDim.x * blockDim.x) >> 6;

  // ---- prologue: load tile-0 state ----
  int tile = gwave;
  bool valid = false; int eIdx = 0, ie = 0, oe = 0;
  float x0 = 0.f, x1 = 0.f, x2 = 0.f;
  float4v f4 = {};
  if (tile < ntiles) {
    eIdx  = tile * 16 + ecol;
    valid = eIdx < E;
    const int eS = valid ? eIdx : 0;
    ie = in_edges[eS]; oe = out_edges[eS];
    x0 = coords[3 * eS]; x1 = coords[3 * eS + 1]; x2 = coords[3 * eS + 2];
    f4 = *(const float4v*)(ef + (size_t)ie * 16 + 4 * q);
  }

  for (; tile < ntiles; tile += nwaves) {
    // ---- prefetch next tile's indices + coords ----
    const int tn = tile + nwaves;
    int eIdxN = 0, ieN = 0, oeN = 0; bool validN = false;
    float x0N = 0.f, x1N = 0.f, x2N = 0.f;
    if (tn < ntiles) {
      eIdxN  = tn * 16 + ecol;
      validN = eIdxN < E;
      const int eSN = validN ? eIdxN : 0;
      ieN = in_edges[eSN]; oeN = out_edges[eSN];
      x0N = coords[3 * eSN]; x1N = coords[3 * eSN + 1]; x2N = coords[3 * eSN + 2];
    }

    // CSR slot for CURRENT tile — atomic latency hides under the MLP
    int pos = 0;
    if (SCATTER_MODE == 0 && q == 0 && valid)
      pos = atomicAdd(&cursor[oe], 1);

    // ---- L1: 3 -> 32 (consts via quad-broadcast LDS reads) ----
    const uint4v w1r0 = *(const uint4v*)&sC1[q][0];
    const uint4v w1r1 = *(const uint4v*)&sC1[q][4];
    const uint4v w1r2 = *(const uint4v*)&sC1[q][8];
    const uint4v b1v  = *(const uint4v*)&sC1[q][12];
    float hv[8];
#pragma unroll
    for (int i = 0; i < 4; ++i) {
      hv[2 * i]     = bflo2f(b1v[i]) + x0 * bflo2f(w1r0[i])
                    + x1 * bflo2f(w1r1[i]) + x2 * bflo2f(w1r2[i]);
      hv[2 * i + 1] = bfhi2f(b1v[i]) + x0 * bfhi2f(w1r0[i])
                    + x1 * bfhi2f(w1r1[i]) + x2 * bfhi2f(w1r2[i]);
    }
    short4v bh[2];
    {
      const uint4v g1v  = *(const uint4v*)&sC2[q][0];
      const uint4v be1v = *(const uint4v*)&sC2[q][4];
      ln_relu_pack(hv, g1v, be1v, bh);
    }

    // ---- L2 GEMM: 32->32 ----
    {
      const uint4v b2v = *(const uint4v*)&sC3[q][0];
#pragma unroll
      for (int t2 = 0; t2 < 2; ++t2) {
        float4v c;
        c[0] = bflo2f(b2v[t2 * 2]);     c[1] = bfhi2f(b2v[t2 * 2]);
        c[2] = bflo2f(b2v[t2 * 2 + 1]); c[3] = bfhi2f(b2v[t2 * 2 + 1]);
        c = mfma16(a2[t2][0], bh[0], c);
        c = mfma16(a2[t2][1], bh[1], c);
        hv[t2 * 4 + 0] = c[0]; hv[t2 * 4 + 1] = c[1];
        hv[t2 * 4 + 2] = c[2]; hv[t2 * 4 + 3] = c[3];
      }
    }
    {
      const uint4v g2v  = *(const uint4v*)&sC2[q][8];
      const uint4v be2v = *(const uint4v*)&sC2[q][12];
      ln_relu_pack(hv, g2v, be2v, bh);
    }

    // ---- prefetch next tile's feature gather (ieN landed by now) ----
    float4v f4N = {};
    if (tn < ntiles)
      f4N = *(const float4v*)(ef + (size_t)ieN * 16 + 4 * q);

    // sum of this quad's 4 f-values (for sumf - 2*dot algebra)
    const float sumf = (f4[0] + f4[1]) + (f4[2] + f4[3]);

    // ---- L3 GEMM (y = 2log2e * (W3 h + b3)) + contraction:
    //      pr = sumf - 2 * sum_j f_j * rcp(exp2(y_j)+1)
#pragma unroll
    for (int og = 0; og < 4; ++og) {
      float pr[4];
#pragma unroll
      for (int r = 0; r < 4; ++r) {
        const int o = og * 4 + r;
        const uint4v av = *(const uint4v*)&sA3[(o * 64 + l) * 4];
        float4v c = *(const float4v*)&sB3f[(o * 4 + q) * 4];
        uint2v t0; t0[0] = av[0]; t0[1] = av[1];
        uint2v t1; t1[0] = av[2]; t1[1] = av[3];
        const short4v a30 = __builtin_bit_cast(short4v, t0);
        const short4v a31 = __builtin_bit_cast(short4v, t1);
        c = mfma16(a30, bh[0], c);
        c = mfma16(a31, bh[1], c);
        float dot = 0.f;
#pragma unroll
        for (int j = 0; j < 4; ++j) {
          const float e = __builtin_amdgcn_exp2f(c[j]);
          const float rr = __builtin_amdgcn_rcpf(e + 1.0f);
          dot = fmaf(f4[j], rr, dot);
        }
        pr[r] = fmaf(-2.0f, dot, sumf);
      }
#pragma unroll
      for (int r = 0; r < 4; ++r) {
        pr[r] += __shfl_xor(pr[r], 16);
        pr[r] += __shfl_xor(pr[r], 32);
      }
      if (SCATTER_MODE == 0) {
        if (q == 0 && valid) {
          float4v s = {pr[0], pr[1], pr[2], pr[3]};
          *(float4v*)(out_ch + (size_t)pos * 16 + og * 4) = s;  // CSR slot
        }
      } else {
        if (q == 0 && valid) {
#pragma unroll
          for (int r = 0; r < 4; ++r)
            atomicAdd(&out_ch[(size_t)oe * 16 + og * 4 + r], pr[r]);
        }
      }
    }
    if (SCATTER_MODE == 1) {
      if (q == 0 && valid) atomicAdd(&aux[oe], 1);
    }

    // rotate pipeline state
    eIdx = eIdxN; valid = validN; ie = ieN; oe = oeN;
    x0 = x0N; x1 = x1N; x2 = x2N; f4 = f4N;
  }
}

// ---------------- per-node reduce (CSR path, contiguous rows) ----------------

__global__ __launch_bounds__(256)
void nf_reduce(const float* __restrict__ out_ch, const int* __restrict__ counts,
               const int* __restrict__ offsets, float* __restrict__ out, int N) {
  const int gid = blockIdx.x * 16 + (threadIdx.x >> 4);
  const int o   = threadIdx.x & 15;
  if (gid >= N) return;
  const int deg = counts[gid];
  const int off = offsets[gid];
  float acc = 0.f;
  for (int d = 0; d < deg; ++d)
    acc += out_ch[(size_t)(off + d) * 16 + o];
  out[(size_t)gid * 16 + o] = acc / fmaxf((float)deg, 1.0f);
}

// fallback divide
__global__ void nf_final(float* __restrict__ out, const int* __restrict__ counts, int n) {
  int i = blockIdx.x * blockDim.x + threadIdx.x;
  if (i < n) {
    float c = (float)counts[i >> 4];
    out[i] = out[i] / fmaxf(c, 1.0f);
  }
}

extern "C" void kernel_launch(void* const* d_in, const int* in_sizes, int n_in,
                              void* d_out, int out_size, void* d_ws, size_t ws_size,
                              hipStream_t stream) {
  const int*   in_edges  = (const int*)d_in[0];
  const int*   out_edges = (const int*)d_in[1];
  const float* ef        = (const float*)d_in[2];
  const float* coords    = (const float*)d_in[3];
  const float* W1  = (const float*)d_in[4];
  const float* b1  = (const float*)d_in[5];
  const float* g1  = (const float*)d_in[6];
  const float* be1 = (const float*)d_in[7];
  const float* W2  = (const float*)d_in[8];
  const float* b2  = (const float*)d_in[9];
  const float* g2  = (const float*)d_in[10];
  const float* be2 = (const float*)d_in[11];
  const float* W3  = (const float*)d_in[12];
  const float* b3  = (const float*)d_in[13];

  const int E = in_sizes[0];
  const int N = in_sizes[2] / 16;
  const int ntiles = (E + 15) / 16;
  float* out = (float*)d_out;

  // ws: out_ch [16E f32] | counts [N] | offsets [N] | cursor [N] | total [1]
  const size_t need = ((size_t)E * 16 + 3 * (size_t)N + 1) * 4;

  if (ws_size >= need) {
    float* out_chv = (float*)d_ws;
    int*   counts  = (int*)(out_chv + (size_t)E * 16);
    int*   offsets = counts + N;
    int*   cursor  = offsets + N;
    int*   total   = cursor + N;

    hipMemsetAsync(counts, 0, ((size_t)3 * N + 1) * sizeof(int), stream);
    nf_hist<<<1024, 256, 0, stream>>>(out_edges, counts, E);
    nf_alloc<<<(N + 255) / 256, 256, 0, stream>>>(counts, offsets, cursor, total, N);
    nf_main<0><<<2048, 256, 0, stream>>>(in_edges, out_edges, ef, coords,
                                         W1, b1, g1, be1, W2, b2, g2, be2, W3, b3,
                                         out_chv, nullptr, cursor, E, ntiles);
    nf_reduce<<<(N + 15) / 16, 256, 0, stream>>>(out_chv, counts, offsets, out, N);
  } else {
    // fallback: direct atomics
    int* counts = (int*)d_ws;
    hipMemsetAsync(out, 0, (size_t)out_size * sizeof(float), stream);
    hipMemsetAsync(counts, 0, (size_t)N * sizeof(int), stream);
    nf_main<1><<<2048, 256, 0, stream>>>(in_edges, out_edges, ef, coords,
                                         W1, b1, g1, be1, W2, b2, g2, be2, W3, b3,
                                         out, counts, nullptr, E, ntiles);
    nf_final<<<(out_size + 255) / 256, 256, 0, stream>>>(out, counts, out_size);
  }
}